// Round 9
// baseline (1637.570 us; speedup 1.0000x reference)
//
#include <hip/hip_runtime.h>

#define BB 16
#define LL 512
#define DD 512
#define ROWS (BB*LL)   // 8192

typedef unsigned short u16;
typedef __attribute__((ext_vector_type(8))) short short8;
typedef __attribute__((ext_vector_type(8))) unsigned short ushort8_t;
typedef __attribute__((ext_vector_type(4))) float f32x4;

__device__ __forceinline__ float b2f(u16 u) {
    return __uint_as_float(((unsigned int)u) << 16);
}
__device__ __forceinline__ u16 f2b(float f) {
    unsigned int u = __float_as_uint(f);
    u += 0x7FFFu + ((u >> 16) & 1u);
    return (u16)(u >> 16);
}
__device__ __forceinline__ float ld1(const void* p, size_t i, int f32) {
    return f32 ? ((const float*)p)[i] : b2f(((const u16*)p)[i]);
}

// Input dtype detector (fp32 vs bf16), see R2 notes.
__global__ void detect(const u16* __restrict__ x, int* __restrict__ flag)
{
    __shared__ int s;
    if (threadIdx.x == 0) s = 0;
    __syncthreads();
    u16 v = x[2 * threadIdx.x] & 0x7FFFu;
    if ((v & 0x7F80u) >= 0x5000u) atomicOr(&s, 1);
    __syncthreads();
    if (threadIdx.x == 0) *flag = s;
}

__global__ __launch_bounds__(256)
void cvt_x(const void* __restrict__ X, float* __restrict__ acc, u16* __restrict__ cur,
           const int* __restrict__ flag)
{
    const int f = *flag;
    size_t i = (size_t)blockIdx.x * 256 + threadIdx.x;
    float v = ld1(X, i, f);
    acc[i] = v;
    cur[i] = f2b(v);
}

__global__ __launch_bounds__(256)
void cvt_copy(const void* __restrict__ src, u16* __restrict__ dst, int n,
              const int* __restrict__ flag)
{
    const int f = *flag;
    int i = blockIdx.x * 256 + threadIdx.x;
    if (i < n) dst[i] = f2b(ld1(src, i, f));
}

// XP2 [E][128][1024] block-diag
__global__ __launch_bounds__(256)
void cvt_xp2(const void* __restrict__ xp, u16* __restrict__ dst,
             const int* __restrict__ flag)
{
    const int f = *flag;
    int i = blockIdx.x * 256 + threadIdx.x;
    int e = i >> 17, r = (i >> 10) & 127, c = i & 1023;
    int dir = r >> 6, n = r & 63;
    float v = ((c >> 9) == dir)
        ? ld1(xp, ((size_t)(e*2 + dir)*64 + n)*512 + (c & 511), f) : 0.f;
    dst[i] = f2b(v);
}

// DT2 [E][1024][128] block-diag
__global__ __launch_bounds__(256)
void cvt_dt2(const void* __restrict__ dw, u16* __restrict__ dst,
             const int* __restrict__ flag)
{
    const int f = *flag;
    int i = blockIdx.x * 256 + threadIdx.x;
    int e = i >> 17, r = (i >> 7) & 1023, c = i & 127;
    int dir = r >> 9, d = r & 511;
    float v = 0.f;
    if (dir == 0 && c < 32)
        v = ld1(dw, ((size_t)(e*2)*512 + d)*32 + c, f);
    else if (dir == 1 && c >= 64 && c < 96)
        v = ld1(dw, ((size_t)(e*2 + 1)*512 + d)*32 + (c - 64), f);
    dst[i] = f2b(v);
}

// OUT2 [E][512][1024] K-concat
__global__ __launch_bounds__(256)
void cvt_out2(const void* __restrict__ ow, u16* __restrict__ dst,
              const int* __restrict__ flag)
{
    const int f = *flag;
    int i = blockIdx.x * 256 + threadIdx.x;
    int e = i >> 19, rest = i & 524287;
    int d = rest >> 10, c = rest & 1023;
    int dir = c >> 9;
    dst[i] = f2b(ld1(ow, ((size_t)(e*2 + dir)*512 + d)*512 + (c & 511), f));
}

__global__ __launch_bounds__(256)
void acc_init(const u16* __restrict__ x, float* __restrict__ o)
{
    size_t i = (size_t)blockIdx.x * 256 + threadIdx.x;
    o[i] = b2f(x[i]);
}

// MFMA GEMM: C[M,N] = act(A @ W[N,K]^T + bias[boff+c]).
// at: A stored transposed [K][M]. tmode: C^T -> Cb[N][M] via LDS with COALESCED
// stores (16 lanes = 256 contiguous B per column; R8's 2-lane/col map was the bug).
// Crm: optional extra row-major bf16 output (used by xp to feed dt at=0).
// 128x128 tile, 4 waves, BK=32, LDS stride 56.
__global__ __launch_bounds__(256)
void gemm_mfma(const u16* __restrict__ A, const u16* __restrict__ W,
               float* __restrict__ Cf, u16* __restrict__ Cb, u16* __restrict__ Crm,
               int M, int N, int K,
               const void* __restrict__ bias, size_t boff, int act, int accum,
               int at, int tmode, const int* __restrict__ flag)
{
    const int f = *flag;
    __shared__ u16 smem[17920];                 // staging (2x128x56) / epilogue (128x140)
    u16 (*As)[56] = (u16 (*)[56])smem;
    u16 (*Ws)[56] = (u16 (*)[56])&smem[7168];
    const int tid  = threadIdx.x;
    const int lane = tid & 63;
    const int wid  = tid >> 6;
    const int wr   = (wid >> 1) * 64;
    const int wc   = (wid & 1) * 64;
    const int row0 = blockIdx.y * 128;
    const int col0 = blockIdx.x * 128;
    const int sr = tid >> 1;
    const int sc = (tid & 1) * 16;
    const int mrow = lane & 15;
    const int kq   = (lane >> 4) * 8;
    const int kk0 = tid & 31, ch0 = tid >> 5, ch1 = ch0 + 8;

    uint4 pa0, pa1, pw0, pw1;
    if (at) {
        pa0 = *(const uint4*)(A + (size_t)kk0 * M + row0 + ch0*8);
        pa1 = *(const uint4*)(A + (size_t)kk0 * M + row0 + ch1*8);
    } else {
        pa0 = *(const uint4*)(A + (size_t)(row0 + sr) * K + sc);
        pa1 = *(const uint4*)(A + (size_t)(row0 + sr) * K + sc + 8);
    }
    pw0 = *(const uint4*)(W + (size_t)(col0 + sr) * K + sc);
    pw1 = *(const uint4*)(W + (size_t)(col0 + sr) * K + sc + 8);

    f32x4 acc[4][4] = {};
    for (int k0 = 0; k0 < K; k0 += 32) {
        if (k0) __syncthreads();
        if (at) {
            const u16* p0 = (const u16*)&pa0;
            const u16* p1 = (const u16*)&pa1;
            #pragma unroll
            for (int j = 0; j < 8; ++j) {
                As[ch0*8 + j][kk0] = p0[j];
                As[ch1*8 + j][kk0] = p1[j];
            }
        } else {
            *(uint4*)&As[sr][sc]     = pa0;
            *(uint4*)&As[sr][sc + 8] = pa1;
        }
        *(uint4*)&Ws[sr][sc]     = pw0;
        *(uint4*)&Ws[sr][sc + 8] = pw1;
        __syncthreads();
        int kn = k0 + 32;
        if (kn < K) {
            if (at) {
                pa0 = *(const uint4*)(A + (size_t)(kn + kk0)*M + row0 + ch0*8);
                pa1 = *(const uint4*)(A + (size_t)(kn + kk0)*M + row0 + ch1*8);
            } else {
                pa0 = *(const uint4*)(A + (size_t)(row0+sr)*K + kn + sc);
                pa1 = *(const uint4*)(A + (size_t)(row0+sr)*K + kn + sc + 8);
            }
            pw0 = *(const uint4*)(W + (size_t)(col0+sr)*K + kn + sc);
            pw1 = *(const uint4*)(W + (size_t)(col0+sr)*K + kn + sc + 8);
        }
        short8 af[4], bfr[4];
        #pragma unroll
        for (int mi = 0; mi < 4; ++mi)
            af[mi] = *(const short8*)&As[wr + mi*16 + mrow][kq];
        #pragma unroll
        for (int ni = 0; ni < 4; ++ni)
            bfr[ni] = *(const short8*)&Ws[wc + ni*16 + mrow][kq];
        #pragma unroll
        for (int mi = 0; mi < 4; ++mi)
            #pragma unroll
            for (int ni = 0; ni < 4; ++ni)
                acc[mi][ni] = __builtin_amdgcn_mfma_f32_16x16x32_bf16(
                    af[mi], bfr[ni], acc[mi][ni], 0, 0, 0);
    }
    const int drow = (lane >> 4) * 4;
    const int dcol = lane & 15;
    if (tmode) {
        __syncthreads();   // staging LDS done
        #pragma unroll
        for (int mi = 0; mi < 4; ++mi) {
            #pragma unroll
            for (int ni = 0; ni < 4; ++ni) {
                int cl = wc + ni*16 + dcol;          // local col 0..127
                int rl = wr + mi*16 + drow;          // local row base
                #pragma unroll
                for (int r = 0; r < 4; ++r) {
                    float v = acc[mi][ni][r];
                    if (bias) v += ld1(bias, boff + col0 + cl, f);
                    if (act == 1) v = (v > 15.f) ? v : log1pf(__expf(v));
                    else if (act == 2) v = 0.5f*v*(1.f + erff(v*0.70710678118f));
                    smem[cl*140 + rl + r] = f2b(v);
                }
            }
        }
        __syncthreads();
        // Coalesced: 16 lanes cover one column's 256 B contiguously.
        const int ecol = tid >> 4;          // 0..15
        const int eoff = (tid & 15) * 8;    // u16 offset 0..120
        #pragma unroll
        for (int q = 0; q < 8; ++q) {
            int c = ecol + q*16;
            *(uint4*)(Cb + (size_t)(col0 + c) * M + row0 + eoff) =
                *(const uint4*)&smem[c*140 + eoff];
        }
        if (Crm) {
            #pragma unroll
            for (int mi = 0; mi < 4; ++mi) {
                #pragma unroll
                for (int ni = 0; ni < 4; ++ni) {
                    int colb = col0 + wc + ni*16 + dcol;
                    int rowb = row0 + wr + mi*16 + drow;
                    #pragma unroll
                    for (int r = 0; r < 4; ++r) {
                        float v = acc[mi][ni][r];
                        if (bias) v += ld1(bias, boff + colb, f);
                        if (act == 1) v = (v > 15.f) ? v : log1pf(__expf(v));
                        else if (act == 2) v = 0.5f*v*(1.f + erff(v*0.70710678118f));
                        Crm[(size_t)(rowb + r) * N + colb] = f2b(v);
                    }
                }
            }
        }
    } else {
        #pragma unroll
        for (int mi = 0; mi < 4; ++mi) {
            #pragma unroll
            for (int ni = 0; ni < 4; ++ni) {
                int colb = col0 + wc + ni*16 + dcol;
                int rowb = row0 + wr + mi*16 + drow;
                #pragma unroll
                for (int r = 0; r < 4; ++r) {
                    float v = acc[mi][ni][r];
                    if (bias) v += ld1(bias, boff + colb, f);
                    if (act == 1) v = (v > 15.f) ? v : log1pf(__expf(v));
                    else if (act == 2) v = 0.5f*v*(1.f + erff(v*0.70710678118f));
                    size_t o = (size_t)(rowb + r) * N + colb;
                    if (accum) Cf[o] += v;
                    else if (Cf) Cf[o] = v;
                    else Cb[o] = f2b(v);
                }
            }
        }
    }
}

// Transposed conv + silu, vectorized. xz_t [2048][8192]; z rows silu'd in place.
__global__ __launch_bounds__(256)
void conv_both(u16* __restrict__ xz, const void* __restrict__ cw,
               const void* __restrict__ cb, u16* __restrict__ xc, int e,
               const int* __restrict__ flag)
{
    const int f = *flag;
    int t = blockIdx.x * 256 + threadIdx.x;
    int chunk = t & 1023;
    int ch = t >> 10;
    int dir = ch >> 9, d = ch & 511;
    int r0 = chunk * 8;
    size_t xbase = ((size_t)(dir*1024 + d))*8192 + r0;
    ushort8_t x8 = *(const ushort8_t*)(xz + xbase);
    float xv[8];
    #pragma unroll
    for (int j = 0; j < 8; ++j) xv[j] = b2f(x8[j]);
    float nb[8];
    if (dir == 0) {
        nb[0] = ((r0 & 511) == 0) ? 0.f : b2f(xz[xbase - 1]);
        #pragma unroll
        for (int j = 1; j < 8; ++j) nb[j] = xv[j-1];
    } else {
        #pragma unroll
        for (int j = 0; j < 7; ++j) nb[j] = xv[j+1];
        nb[7] = (((r0 + 7) & 511) == 511) ? 0.f : b2f(xz[xbase + 8]);
    }
    size_t co = (size_t)(e*2 + dir)*1024 + 2*d;
    float w0 = ld1(cw, co, f), w1 = ld1(cw, co + 1, f);
    float bb = ld1(cb, (size_t)(e*2 + dir)*512 + d, f);
    ushort8_t o8;
    #pragma unroll
    for (int j = 0; j < 8; ++j) {
        float v = w0*nb[j] + w1*xv[j] + bb;
        o8[j] = f2b(v / (1.f + __expf(-v)));
    }
    *(ushort8_t*)(xc + (size_t)ch*8192 + r0) = o8;
    size_t zbase = ((size_t)(dir*1024 + 512 + d))*8192 + r0;
    ushort8_t z8 = *(const ushort8_t*)(xz + zbase);
    #pragma unroll
    for (int j = 0; j < 8; ++j) {
        float z = b2f(z8[j]);
        z8[j] = f2b(z / (1.f + __expf(-z)));
    }
    *(ushort8_t*)(xz + zbase) = z8;
}

// Selective scan, transposed layouts, dir-specialized (compile-time vec indices).
#define SCAN_STEP(jj) { \
    float dtv = b2f(dt8[jj]); \
    float xv  = b2f(xv8[jj]); \
    h = __expf(dtv * Av) * h + dtv * b2f(Bn8[jj]) * xv; \
    float c = h * b2f(Cn8[jj]); \
    c += __shfl_xor(c, 8); \
    c += __shfl_xor(c, 4); \
    c += __shfl_xor(c, 2); \
    c += __shfl_xor(c, 1); \
    g8[jj] = f2b((c + Dv * xv) * b2f(zs8[jj])); \
}

__global__ __launch_bounds__(256)
void ssm_scan(u16* __restrict__ dtg, const u16* __restrict__ xc,
              const u16* __restrict__ proj, const u16* __restrict__ xz,
              const void* __restrict__ A_log, const void* __restrict__ Dsk, int e,
              const int* __restrict__ flag)
{
    const int f = *flag;
    int lane = threadIdx.x & 15;
    int gg = blockIdx.x * 16 + (threadIdx.x >> 4);
    int dir = gg >> 13;
    int rem = gg & 8191;
    int b = rem >> 9, d = rem & 511;
    int ed = e*2 + dir;
    float Av = -__expf(ld1(A_log, (size_t)ed*8192 + d*16 + lane, f));
    float Dv = ld1(Dsk, (size_t)ed*512 + d, f);
    int ch = dir*512 + d;
    u16* dtp = dtg + (size_t)ch*8192;
    const u16* xcp = xc + (size_t)ch*8192;
    const u16* zp  = xz + ((size_t)(dir*1024 + 512 + d))*8192;
    const u16* Bp  = proj + ((size_t)(dir*64 + 32 + lane))*8192;
    const u16* Cp  = Bp + (size_t)16*8192;
    float h = 0.f;
    size_t rb = (size_t)b * LL;
    if (dir == 0) {
        for (int s0 = 0; s0 < LL; s0 += 8) {
            size_t base = rb + s0;
            ushort8_t dt8 = *(const ushort8_t*)(dtp + base);
            ushort8_t xv8 = *(const ushort8_t*)(xcp + base);
            ushort8_t zs8 = *(const ushort8_t*)(zp + base);
            ushort8_t Bn8 = *(const ushort8_t*)(Bp + base);
            ushort8_t Cn8 = *(const ushort8_t*)(Cp + base);
            ushort8_t g8;
            SCAN_STEP(0) SCAN_STEP(1) SCAN_STEP(2) SCAN_STEP(3)
            SCAN_STEP(4) SCAN_STEP(5) SCAN_STEP(6) SCAN_STEP(7)
            if (lane == 0)
                *(ushort8_t*)(dtp + base) = g8;
        }
    } else {
        for (int s0 = 0; s0 < LL; s0 += 8) {
            size_t base = rb + (LL - 8 - s0);
            ushort8_t dt8 = *(const ushort8_t*)(dtp + base);
            ushort8_t xv8 = *(const ushort8_t*)(xcp + base);
            ushort8_t zs8 = *(const ushort8_t*)(zp + base);
            ushort8_t Bn8 = *(const ushort8_t*)(Bp + base);
            ushort8_t Cn8 = *(const ushort8_t*)(Cp + base);
            ushort8_t g8;
            SCAN_STEP(7) SCAN_STEP(6) SCAN_STEP(5) SCAN_STEP(4)
            SCAN_STEP(3) SCAN_STEP(2) SCAN_STEP(1) SCAN_STEP(0)
            if (lane == 0)
                *(ushort8_t*)(dtp + base) = g8;
        }
    }
}

__global__ __launch_bounds__(256)
void lnorm(const u16* __restrict__ Xb, const float* __restrict__ Xf,
           const void* __restrict__ w, size_t wo, const void* __restrict__ b, size_t bo,
           void* __restrict__ out, int omode, const int* __restrict__ flag)
{
    const int f = *flag;
    int wid = (blockIdx.x * 256 + threadIdx.x) >> 6;
    int lane = threadIdx.x & 63;
    size_t base = (size_t)wid * DD;
    float v[8];
    float s = 0.f;
    #pragma unroll
    for (int i = 0; i < 8; ++i) {
        int c = lane + i*64;
        float t = 0.f;
        if (Xb) t += b2f(Xb[base + c]);
        if (Xf) t += Xf[base + c];
        v[i] = t; s += t;
    }
    #pragma unroll
    for (int off = 32; off > 0; off >>= 1) s += __shfl_xor(s, off);
    float mean = s * (1.f/512.f);
    float var = 0.f;
    #pragma unroll
    for (int i = 0; i < 8; ++i) { float dlt = v[i] - mean; var += dlt*dlt; }
    #pragma unroll
    for (int off = 32; off > 0; off >>= 1) var += __shfl_xor(var, off);
    float rstd = rsqrtf(var * (1.f/512.f) + 1e-5f);
    #pragma unroll
    for (int i = 0; i < 8; ++i) {
        int c = lane + i*64;
        float o = (v[i] - mean) * rstd * ld1(w, wo + c, f) + ld1(b, bo + c, f);
        if (omode && f) ((float*)out)[base + c] = o;
        else            ((u16*)out)[base + c] = f2b(o);
    }
}

extern "C" void kernel_launch(void* const* d_in, const int* in_sizes, int n_in,
                              void* d_out, int out_size, void* d_ws, size_t ws_size,
                              hipStream_t stream)
{
    (void)in_sizes; (void)n_in; (void)out_size; (void)ws_size;
    const void* X       = d_in[0];
    const void* in_w    = d_in[1];
    const void* conv_w  = d_in[2];
    const void* conv_b  = d_in[3];
    const void* xproj_w = d_in[4];
    const void* dt_w    = d_in[5];
    const void* dt_b    = d_in[6];
    const void* A_log   = d_in[7];
    const void* D_skip  = d_in[8];
    const void* out_w   = d_in[9];
    const void* ffn1_w  = d_in[10];
    const void* ffn1_b  = d_in[11];
    const void* ffn2_w  = d_in[12];
    const void* ffn2_b  = d_in[13];
    const void* n1_w    = d_in[14];
    const void* n1_b    = d_in[15];
    const void* n2_w    = d_in[16];
    const void* n2_b    = d_in[17];
    const void* fn_w    = d_in[18];
    const void* fn_b    = d_in[19];

    // Workspace map (R6/R7 notes). proj_rm lives in cur's dead 2nd half-lifetime.
    char* p = (char*)d_ws;
    float* acc  = (float*)(p);
    u16*   cur  = (u16*)(p + 16777216);
    u16*   xz   = (u16*)(p + 25165824);
    u16*   xc   = (u16*)(p + 58720256);
    u16*   dtg  = (u16*)(p + 75497472);
    u16*   proj = (u16*)(p + 92274688);
    int*   flag = (int*)(p + 94371840);
    u16*   wbf  = (u16*)(p + 94375936);
    u16*   ffh  = xz;
    float* y2   = (float*)xc;
    u16*   x1   = dtg;
    u16*   projrm = cur;   // [8192][128] bf16, 2 MB; cur dead between in-proj & lnorm-n2
    const size_t W_IN  = 0;
    const size_t W_XP  = 2097152;
    const size_t W_DT  = 2359296;
    const size_t W_OUT = 2621440;
    const size_t W_FF1 = 3670016;
    const size_t W_FF2 = 5767168;

    detect<<<1, 512, 0, stream>>>((const u16*)X, flag);
    cvt_x<<<ROWS*DD/256, 256, 0, stream>>>(X, acc, cur, flag);
    cvt_copy<<<2097152/256, 256, 0, stream>>>(in_w,   wbf + W_IN,  2097152, flag);
    cvt_copy<<<2097152/256, 256, 0, stream>>>(ffn1_w, wbf + W_FF1, 2097152, flag);
    cvt_copy<<<2097152/256, 256, 0, stream>>>(ffn2_w, wbf + W_FF2, 2097152, flag);
    cvt_xp2<<<262144/256, 256, 0, stream>>>(xproj_w, wbf + W_XP, flag);
    cvt_dt2<<<262144/256, 256, 0, stream>>>(dt_w, wbf + W_DT, flag);
    cvt_out2<<<1048576/256, 256, 0, stream>>>(out_w, wbf + W_OUT, flag);

    for (int e = 0; e < 2; ++e) {
        if (e == 1)
            acc_init<<<ROWS*DD/256, 256, 0, stream>>>(cur, acc);
        // xz_t = (cur @ [in_f;in_r]^T)^T : [2048][8192]
        gemm_mfma<<<dim3(16,64), 256, 0, stream>>>(
            cur, wbf + W_IN + (size_t)e*1048576, nullptr, xz, nullptr,
            ROWS, 2048, 512, nullptr, 0, 0, 0, 0, 1, flag);
        conv_both<<<4096, 256, 0, stream>>>(xz, conv_w, conv_b, xc, e, flag);
        // proj_t [128][8192] + proj_rm [8192][128] = xc @ XP2^T  (A = xc_t, at=1)
        gemm_mfma<<<dim3(1,64), 256, 0, stream>>>(
            xc, wbf + W_XP + (size_t)e*131072, nullptr, proj, projrm,
            ROWS, 128, 1024, nullptr, 0, 0, 0, 1, 1, flag);
        // dtg_t = softplus(proj_rm @ DT2^T + dt_b)^T : [1024][8192]  (at=0 now)
        gemm_mfma<<<dim3(8,64), 256, 0, stream>>>(
            projrm, wbf + W_DT + (size_t)e*131072, nullptr, dtg, nullptr,
            ROWS, 1024, 128, dt_b, (size_t)e*1024, 1, 0, 0, 1, flag);
        ssm_scan<<<1024, 256, 0, stream>>>(dtg, xc, proj, xz, A_log, D_skip, e, flag);
        // acc += g @ OUT2^T : [8192,512]  (A = g_t, at=1)
        gemm_mfma<<<dim3(4,64), 256, 0, stream>>>(
            dtg, wbf + W_OUT + (size_t)e*524288, acc, nullptr, nullptr,
            ROWS, 512, 1024, nullptr, 0, 0, 1, 1, 0, flag);
        size_t eo = (size_t)e * 512;
        lnorm<<<2048, 256, 0, stream>>>(nullptr, acc, n1_w, eo, n1_b, eo, x1, 0, flag);
        gemm_mfma<<<dim3(16,64), 256, 0, stream>>>(
            x1, wbf + W_FF1 + (size_t)e*1048576, nullptr, ffh, nullptr,
            ROWS, 2048, 512, ffn1_b, (size_t)e*2048, 2, 0, 0, 0, flag);
        gemm_mfma<<<dim3(4,64), 256, 0, stream>>>(
            ffh, wbf + W_FF2 + (size_t)e*1048576, y2, nullptr, nullptr,
            ROWS, 512, 2048, ffn2_b, eo, 0, 0, 0, 0, flag);
        lnorm<<<2048, 256, 0, stream>>>(x1, y2, n2_w, eo, n2_b, eo, cur, 0, flag);
    }
    lnorm<<<2048, 256, 0, stream>>>(cur, nullptr, fn_w, 0, fn_b, 0, d_out, 1, flag);
}

// Round 10
// 1365.082 us; speedup vs baseline: 1.1996x; 1.1996x over previous
//
#include <hip/hip_runtime.h>

#define BB 16
#define LL 512
#define DD 512
#define ROWS (BB*LL)   // 8192

typedef unsigned short u16;
typedef __attribute__((ext_vector_type(8))) short short8;
typedef __attribute__((ext_vector_type(8))) unsigned short ushort8_t;
typedef __attribute__((ext_vector_type(4))) float f32x4;

__device__ __forceinline__ float b2f(u16 u) {
    return __uint_as_float(((unsigned int)u) << 16);
}
__device__ __forceinline__ u16 f2b(float f) {
    unsigned int u = __float_as_uint(f);
    u += 0x7FFFu + ((u >> 16) & 1u);
    return (u16)(u >> 16);
}
__device__ __forceinline__ float ld1(const void* p, size_t i, int f32) {
    return f32 ? ((const float*)p)[i] : b2f(((const u16*)p)[i]);
}

// Direct global->LDS DMA, 16 B per lane. LDS side = lptr + lane*16 (wave-uniform lptr!).
__device__ __forceinline__ void gload16(const u16* g, u16* l) {
    __builtin_amdgcn_global_load_lds(
        (const __attribute__((address_space(1))) unsigned int*)g,
        (__attribute__((address_space(3))) unsigned int*)l, 16, 0, 0);
}

// Input dtype detector (fp32 vs bf16), see R2 notes.
__global__ void detect(const u16* __restrict__ x, int* __restrict__ flag)
{
    __shared__ int s;
    if (threadIdx.x == 0) s = 0;
    __syncthreads();
    u16 v = x[2 * threadIdx.x] & 0x7FFFu;
    if ((v & 0x7F80u) >= 0x5000u) atomicOr(&s, 1);
    __syncthreads();
    if (threadIdx.x == 0) *flag = s;
}

__global__ __launch_bounds__(256)
void cvt_x(const void* __restrict__ X, float* __restrict__ acc, u16* __restrict__ cur,
           const int* __restrict__ flag)
{
    const int f = *flag;
    size_t i = (size_t)blockIdx.x * 256 + threadIdx.x;
    float v = ld1(X, i, f);
    acc[i] = v;
    cur[i] = f2b(v);
}

__global__ __launch_bounds__(256)
void cvt_copy(const void* __restrict__ src, u16* __restrict__ dst, int n,
              const int* __restrict__ flag)
{
    const int f = *flag;
    int i = blockIdx.x * 256 + threadIdx.x;
    if (i < n) dst[i] = f2b(ld1(src, i, f));
}

// XP2 [E][128][1024] block-diag
__global__ __launch_bounds__(256)
void cvt_xp2(const void* __restrict__ xp, u16* __restrict__ dst,
             const int* __restrict__ flag)
{
    const int f = *flag;
    int i = blockIdx.x * 256 + threadIdx.x;
    int e = i >> 17, r = (i >> 10) & 127, c = i & 1023;
    int dir = r >> 6, n = r & 63;
    float v = ((c >> 9) == dir)
        ? ld1(xp, ((size_t)(e*2 + dir)*64 + n)*512 + (c & 511), f) : 0.f;
    dst[i] = f2b(v);
}

// DT2 [E][1024][128] block-diag
__global__ __launch_bounds__(256)
void cvt_dt2(const void* __restrict__ dw, u16* __restrict__ dst,
             const int* __restrict__ flag)
{
    const int f = *flag;
    int i = blockIdx.x * 256 + threadIdx.x;
    int e = i >> 17, r = (i >> 7) & 1023, c = i & 127;
    int dir = r >> 9, d = r & 511;
    float v = 0.f;
    if (dir == 0 && c < 32)
        v = ld1(dw, ((size_t)(e*2)*512 + d)*32 + c, f);
    else if (dir == 1 && c >= 64 && c < 96)
        v = ld1(dw, ((size_t)(e*2 + 1)*512 + d)*32 + (c - 64), f);
    dst[i] = f2b(v);
}

// OUT2 [E][512][1024] K-concat
__global__ __launch_bounds__(256)
void cvt_out2(const void* __restrict__ ow, u16* __restrict__ dst,
              const int* __restrict__ flag)
{
    const int f = *flag;
    int i = blockIdx.x * 256 + threadIdx.x;
    int e = i >> 19, rest = i & 524287;
    int d = rest >> 10, c = rest & 1023;
    int dir = c >> 9;
    dst[i] = f2b(ld1(ow, ((size_t)(e*2 + dir)*512 + d)*512 + (c & 511), f));
}

__global__ __launch_bounds__(256)
void acc_init(const u16* __restrict__ x, float* __restrict__ o)
{
    size_t i = (size_t)blockIdx.x * 256 + threadIdx.x;
    o[i] = b2f(x[i]);
}

// MFMA GEMM: C[M,N] = act(A @ W[N,K]^T + bias[boff+c]).
// Staging: global_load_lds width=16 into UNPADDED [128][32] tiles with XOR-chunk
// swizzle (chunk ^= (row>>1)&3) applied on the GLOBAL address side -> <=2-way
// (free) bank aliasing on ds_read_b128 frag reads. LDS 17.4 KB (was 35.8).
// at: A stored transposed [K][M] (manual scalar staging into swizzled layout).
// tmode: C^T -> Cb[N][M] via staging-buffer reuse, two 64-col halves.
// Crm: optional extra row-major output. 128x128 tile, 4 waves, BK=32.
__global__ __launch_bounds__(256)
void gemm_mfma(const u16* __restrict__ A, const u16* __restrict__ W,
               float* __restrict__ Cf, u16* __restrict__ Cb, u16* __restrict__ Crm,
               int M, int N, int K,
               const void* __restrict__ bias, size_t boff, int act, int accum,
               int at, int tmode, const int* __restrict__ flag)
{
    const int f = *flag;
    __shared__ u16 smem[8704];          // staging A[4096]+W[4096]; epilogue [64][136]
    u16* Asm = smem;
    u16* Wsm = smem + 4096;
    const int tid  = threadIdx.x;
    const int lane = tid & 63;
    const int wid  = tid >> 6;
    const int wr   = (wid >> 1) * 64;
    const int wc   = (wid & 1) * 64;
    const int row0 = blockIdx.y * 128;
    const int col0 = blockIdx.x * 128;
    const int mrow = lane & 15;
    const int q    = lane >> 4;          // k-chunk 0..3

    // DMA lane addressing: wave covers local rows [wid*32, wid*32+32), 2 instrs x 16 rows
    const int r0 = wid*32 + (lane >> 2);
    const int r1 = r0 + 16;
    const int c0 = (((lane & 3) ^ ((r0 >> 1) & 3)) << 3);
    const int c1 = (((lane & 3) ^ ((r1 >> 1) & 3)) << 3);
    const u16* gW0 = W + (size_t)(col0 + r0)*K + c0;
    const u16* gW1 = W + (size_t)(col0 + r1)*K + c1;
    u16* lW0 = Wsm + (wid*32)*32;
    u16* lW1 = Wsm + (wid*32 + 16)*32;
    const u16* gA0 = A;                  // valid only when !at
    const u16* gA1 = A;
    u16* lA0 = Asm + (wid*32)*32;
    u16* lA1 = Asm + (wid*32 + 16)*32;
    if (!at) {
        gA0 = A + (size_t)(row0 + r0)*K + c0;
        gA1 = A + (size_t)(row0 + r1)*K + c1;
    }
    const int kk0 = tid & 31, ch0 = tid >> 5, ch1 = ch0 + 8;   // at-mode staging

    f32x4 acc[4][4] = {};
    for (int k0 = 0; k0 < K; k0 += 32) {
        if (k0) __syncthreads();
        gload16(gW0 + k0, lW0);
        gload16(gW1 + k0, lW1);
        if (!at) {
            gload16(gA0 + k0, lA0);
            gload16(gA1 + k0, lA1);
        } else {
            uint4 a0 = *(const uint4*)(A + (size_t)(k0 + kk0)*M + row0 + ch0*8);
            uint4 a1 = *(const uint4*)(A + (size_t)(k0 + kk0)*M + row0 + ch1*8);
            const u16* p0 = (const u16*)&a0;
            const u16* p1 = (const u16*)&a1;
            const int cch = kk0 >> 3, klow = kk0 & 7;
            #pragma unroll
            for (int jm = 0; jm < 8; ++jm) {
                int m0 = ch0*8 + jm;
                Asm[m0*32 + ((cch ^ ((m0 >> 1) & 3)) << 3) + klow] = p0[jm];
                int m1 = ch1*8 + jm;
                Asm[m1*32 + ((cch ^ ((m1 >> 1) & 3)) << 3) + klow] = p1[jm];
            }
        }
        __builtin_amdgcn_s_waitcnt(0);   // drain DMA (and LDS writes) before barrier
        __syncthreads();
        short8 af[4], bfr[4];
        #pragma unroll
        for (int mi = 0; mi < 4; ++mi) {
            int r = wr + mi*16 + mrow;
            af[mi] = *(const short8*)&Asm[r*32 + ((q ^ ((r >> 1) & 3)) << 3)];
        }
        #pragma unroll
        for (int ni = 0; ni < 4; ++ni) {
            int r = wc + ni*16 + mrow;
            bfr[ni] = *(const short8*)&Wsm[r*32 + ((q ^ ((r >> 1) & 3)) << 3)];
        }
        #pragma unroll
        for (int mi = 0; mi < 4; ++mi)
            #pragma unroll
            for (int ni = 0; ni < 4; ++ni)
                acc[mi][ni] = __builtin_amdgcn_mfma_f32_16x16x32_bf16(
                    af[mi], bfr[ni], acc[mi][ni], 0, 0, 0);
    }
    const int drow = (lane >> 4) * 4;
    const int dcol = lane & 15;
    if (tmode) {
        #pragma unroll
        for (int h = 0; h < 2; ++h) {
            __syncthreads();
            if ((wid & 1) == h) {
                #pragma unroll
                for (int mi = 0; mi < 4; ++mi) {
                    #pragma unroll
                    for (int ni = 0; ni < 4; ++ni) {
                        int cl = ni*16 + dcol;               // 0..63 within half
                        int rl = wr + mi*16 + drow;
                        int colg = col0 + h*64 + cl;
                        #pragma unroll
                        for (int r = 0; r < 4; ++r) {
                            float v = acc[mi][ni][r];
                            if (bias) v += ld1(bias, boff + colg, f);
                            if (act == 1) v = (v > 15.f) ? v : log1pf(__expf(v));
                            else if (act == 2) v = 0.5f*v*(1.f + erff(v*0.70710678118f));
                            smem[cl*136 + rl + r] = f2b(v);
                        }
                    }
                }
            }
            __syncthreads();
            int cl2 = tid >> 2;
            int rb2 = (tid & 3) * 8;
            u16* dstc = Cb + (size_t)(col0 + h*64 + cl2)*M + row0;
            #pragma unroll
            for (int qq = 0; qq < 4; ++qq)
                *(uint4*)(dstc + rb2 + qq*32) = *(const uint4*)&smem[cl2*136 + rb2 + qq*32];
        }
        if (Crm) {
            #pragma unroll
            for (int mi = 0; mi < 4; ++mi) {
                #pragma unroll
                for (int ni = 0; ni < 4; ++ni) {
                    int colb = col0 + wc + ni*16 + dcol;
                    int rowb = row0 + wr + mi*16 + drow;
                    #pragma unroll
                    for (int r = 0; r < 4; ++r) {
                        float v = acc[mi][ni][r];
                        if (bias) v += ld1(bias, boff + colb, f);
                        if (act == 1) v = (v > 15.f) ? v : log1pf(__expf(v));
                        else if (act == 2) v = 0.5f*v*(1.f + erff(v*0.70710678118f));
                        Crm[(size_t)(rowb + r) * N + colb] = f2b(v);
                    }
                }
            }
        }
    } else {
        #pragma unroll
        for (int mi = 0; mi < 4; ++mi) {
            #pragma unroll
            for (int ni = 0; ni < 4; ++ni) {
                int colb = col0 + wc + ni*16 + dcol;
                int rowb = row0 + wr + mi*16 + drow;
                #pragma unroll
                for (int r = 0; r < 4; ++r) {
                    float v = acc[mi][ni][r];
                    if (bias) v += ld1(bias, boff + colb, f);
                    if (act == 1) v = (v > 15.f) ? v : log1pf(__expf(v));
                    else if (act == 2) v = 0.5f*v*(1.f + erff(v*0.70710678118f));
                    size_t o = (size_t)(rowb + r) * N + colb;
                    if (accum) Cf[o] += v;
                    else if (Cf) Cf[o] = v;
                    else Cb[o] = f2b(v);
                }
            }
        }
    }
}

// Transposed conv + silu, vectorized. xz_t [2048][8192]; z rows silu'd in place.
__global__ __launch_bounds__(256)
void conv_both(u16* __restrict__ xz, const void* __restrict__ cw,
               const void* __restrict__ cb, u16* __restrict__ xc, int e,
               const int* __restrict__ flag)
{
    const int f = *flag;
    int t = blockIdx.x * 256 + threadIdx.x;
    int chunk = t & 1023;
    int ch = t >> 10;
    int dir = ch >> 9, d = ch & 511;
    int r0 = chunk * 8;
    size_t xbase = ((size_t)(dir*1024 + d))*8192 + r0;
    ushort8_t x8 = *(const ushort8_t*)(xz + xbase);
    float xv[8];
    #pragma unroll
    for (int j = 0; j < 8; ++j) xv[j] = b2f(x8[j]);
    float nb[8];
    if (dir == 0) {
        nb[0] = ((r0 & 511) == 0) ? 0.f : b2f(xz[xbase - 1]);
        #pragma unroll
        for (int j = 1; j < 8; ++j) nb[j] = xv[j-1];
    } else {
        #pragma unroll
        for (int j = 0; j < 7; ++j) nb[j] = xv[j+1];
        nb[7] = (((r0 + 7) & 511) == 511) ? 0.f : b2f(xz[xbase + 8]);
    }
    size_t co = (size_t)(e*2 + dir)*1024 + 2*d;
    float w0 = ld1(cw, co, f), w1 = ld1(cw, co + 1, f);
    float bb = ld1(cb, (size_t)(e*2 + dir)*512 + d, f);
    ushort8_t o8;
    #pragma unroll
    for (int j = 0; j < 8; ++j) {
        float v = w0*nb[j] + w1*xv[j] + bb;
        o8[j] = f2b(v / (1.f + __expf(-v)));
    }
    *(ushort8_t*)(xc + (size_t)ch*8192 + r0) = o8;
    size_t zbase = ((size_t)(dir*1024 + 512 + d))*8192 + r0;
    ushort8_t z8 = *(const ushort8_t*)(xz + zbase);
    #pragma unroll
    for (int j = 0; j < 8; ++j) {
        float z = b2f(z8[j]);
        z8[j] = f2b(z / (1.f + __expf(-z)));
    }
    *(ushort8_t*)(xz + zbase) = z8;
}

// Selective scan, transposed layouts, dir-specialized (compile-time vec indices).
#define SCAN_STEP(jj) { \
    float dtv = b2f(dt8[jj]); \
    float xv  = b2f(xv8[jj]); \
    h = __expf(dtv * Av) * h + dtv * b2f(Bn8[jj]) * xv; \
    float c = h * b2f(Cn8[jj]); \
    c += __shfl_xor(c, 8); \
    c += __shfl_xor(c, 4); \
    c += __shfl_xor(c, 2); \
    c += __shfl_xor(c, 1); \
    g8[jj] = f2b((c + Dv * xv) * b2f(zs8[jj])); \
}

__global__ __launch_bounds__(256)
void ssm_scan(u16* __restrict__ dtg, const u16* __restrict__ xc,
              const u16* __restrict__ proj, const u16* __restrict__ xz,
              const void* __restrict__ A_log, const void* __restrict__ Dsk, int e,
              const int* __restrict__ flag)
{
    const int f = *flag;
    int lane = threadIdx.x & 15;
    int gg = blockIdx.x * 16 + (threadIdx.x >> 4);
    int dir = gg >> 13;
    int rem = gg & 8191;
    int b = rem >> 9, d = rem & 511;
    int ed = e*2 + dir;
    float Av = -__expf(ld1(A_log, (size_t)ed*8192 + d*16 + lane, f));
    float Dv = ld1(Dsk, (size_t)ed*512 + d, f);
    int ch = dir*512 + d;
    u16* dtp = dtg + (size_t)ch*8192;
    const u16* xcp = xc + (size_t)ch*8192;
    const u16* zp  = xz + ((size_t)(dir*1024 + 512 + d))*8192;
    const u16* Bp  = proj + ((size_t)(dir*64 + 32 + lane))*8192;
    const u16* Cp  = Bp + (size_t)16*8192;
    float h = 0.f;
    size_t rb = (size_t)b * LL;
    if (dir == 0) {
        for (int s0 = 0; s0 < LL; s0 += 8) {
            size_t base = rb + s0;
            ushort8_t dt8 = *(const ushort8_t*)(dtp + base);
            ushort8_t xv8 = *(const ushort8_t*)(xcp + base);
            ushort8_t zs8 = *(const ushort8_t*)(zp + base);
            ushort8_t Bn8 = *(const ushort8_t*)(Bp + base);
            ushort8_t Cn8 = *(const ushort8_t*)(Cp + base);
            ushort8_t g8;
            SCAN_STEP(0) SCAN_STEP(1) SCAN_STEP(2) SCAN_STEP(3)
            SCAN_STEP(4) SCAN_STEP(5) SCAN_STEP(6) SCAN_STEP(7)
            if (lane == 0)
                *(ushort8_t*)(dtp + base) = g8;
        }
    } else {
        for (int s0 = 0; s0 < LL; s0 += 8) {
            size_t base = rb + (LL - 8 - s0);
            ushort8_t dt8 = *(const ushort8_t*)(dtp + base);
            ushort8_t xv8 = *(const ushort8_t*)(xcp + base);
            ushort8_t zs8 = *(const ushort8_t*)(zp + base);
            ushort8_t Bn8 = *(const ushort8_t*)(Bp + base);
            ushort8_t Cn8 = *(const ushort8_t*)(Cp + base);
            ushort8_t g8;
            SCAN_STEP(7) SCAN_STEP(6) SCAN_STEP(5) SCAN_STEP(4)
            SCAN_STEP(3) SCAN_STEP(2) SCAN_STEP(1) SCAN_STEP(0)
            if (lane == 0)
                *(ushort8_t*)(dtp + base) = g8;
        }
    }
}

__global__ __launch_bounds__(256)
void lnorm(const u16* __restrict__ Xb, const float* __restrict__ Xf,
           const void* __restrict__ w, size_t wo, const void* __restrict__ b, size_t bo,
           void* __restrict__ out, int omode, const int* __restrict__ flag)
{
    const int f = *flag;
    int wid = (blockIdx.x * 256 + threadIdx.x) >> 6;
    int lane = threadIdx.x & 63;
    size_t base = (size_t)wid * DD;
    float v[8];
    float s = 0.f;
    #pragma unroll
    for (int i = 0; i < 8; ++i) {
        int c = lane + i*64;
        float t = 0.f;
        if (Xb) t += b2f(Xb[base + c]);
        if (Xf) t += Xf[base + c];
        v[i] = t; s += t;
    }
    #pragma unroll
    for (int off = 32; off > 0; off >>= 1) s += __shfl_xor(s, off);
    float mean = s * (1.f/512.f);
    float var = 0.f;
    #pragma unroll
    for (int i = 0; i < 8; ++i) { float dlt = v[i] - mean; var += dlt*dlt; }
    #pragma unroll
    for (int off = 32; off > 0; off >>= 1) var += __shfl_xor(var, off);
    float rstd = rsqrtf(var * (1.f/512.f) + 1e-5f);
    #pragma unroll
    for (int i = 0; i < 8; ++i) {
        int c = lane + i*64;
        float o = (v[i] - mean) * rstd * ld1(w, wo + c, f) + ld1(b, bo + c, f);
        if (omode && f) ((float*)out)[base + c] = o;
        else            ((u16*)out)[base + c] = f2b(o);
    }
}

extern "C" void kernel_launch(void* const* d_in, const int* in_sizes, int n_in,
                              void* d_out, int out_size, void* d_ws, size_t ws_size,
                              hipStream_t stream)
{
    (void)in_sizes; (void)n_in; (void)out_size; (void)ws_size;
    const void* X       = d_in[0];
    const void* in_w    = d_in[1];
    const void* conv_w  = d_in[2];
    const void* conv_b  = d_in[3];
    const void* xproj_w = d_in[4];
    const void* dt_w    = d_in[5];
    const void* dt_b    = d_in[6];
    const void* A_log   = d_in[7];
    const void* D_skip  = d_in[8];
    const void* out_w   = d_in[9];
    const void* ffn1_w  = d_in[10];
    const void* ffn1_b  = d_in[11];
    const void* ffn2_w  = d_in[12];
    const void* ffn2_b  = d_in[13];
    const void* n1_w    = d_in[14];
    const void* n1_b    = d_in[15];
    const void* n2_w    = d_in[16];
    const void* n2_b    = d_in[17];
    const void* fn_w    = d_in[18];
    const void* fn_b    = d_in[19];

    // Workspace map (R6/R7 notes). proj_rm lives in cur's dead 2nd half-lifetime.
    char* p = (char*)d_ws;
    float* acc  = (float*)(p);
    u16*   cur  = (u16*)(p + 16777216);
    u16*   xz   = (u16*)(p + 25165824);
    u16*   xc   = (u16*)(p + 58720256);
    u16*   dtg  = (u16*)(p + 75497472);
    u16*   proj = (u16*)(p + 92274688);
    int*   flag = (int*)(p + 94371840);
    u16*   wbf  = (u16*)(p + 94375936);
    u16*   ffh  = xz;
    float* y2   = (float*)xc;
    u16*   x1   = dtg;
    u16*   projrm = cur;   // [8192][128] bf16; cur dead between in-proj & lnorm-n2
    const size_t W_IN  = 0;
    const size_t W_XP  = 2097152;
    const size_t W_DT  = 2359296;
    const size_t W_OUT = 2621440;
    const size_t W_FF1 = 3670016;
    const size_t W_FF2 = 5767168;

    detect<<<1, 512, 0, stream>>>((const u16*)X, flag);
    cvt_x<<<ROWS*DD/256, 256, 0, stream>>>(X, acc, cur, flag);
    cvt_copy<<<2097152/256, 256, 0, stream>>>(in_w,   wbf + W_IN,  2097152, flag);
    cvt_copy<<<2097152/256, 256, 0, stream>>>(ffn1_w, wbf + W_FF1, 2097152, flag);
    cvt_copy<<<2097152/256, 256, 0, stream>>>(ffn2_w, wbf + W_FF2, 2097152, flag);
    cvt_xp2<<<262144/256, 256, 0, stream>>>(xproj_w, wbf + W_XP, flag);
    cvt_dt2<<<262144/256, 256, 0, stream>>>(dt_w, wbf + W_DT, flag);
    cvt_out2<<<1048576/256, 256, 0, stream>>>(out_w, wbf + W_OUT, flag);

    for (int e = 0; e < 2; ++e) {
        if (e == 1)
            acc_init<<<ROWS*DD/256, 256, 0, stream>>>(cur, acc);
        // xz_t = (cur @ [in_f;in_r]^T)^T : [2048][8192]
        gemm_mfma<<<dim3(16,64), 256, 0, stream>>>(
            cur, wbf + W_IN + (size_t)e*1048576, nullptr, xz, nullptr,
            ROWS, 2048, 512, nullptr, 0, 0, 0, 0, 1, flag);
        conv_both<<<4096, 256, 0, stream>>>(xz, conv_w, conv_b, xc, e, flag);
        // proj_t [128][8192] + proj_rm [8192][128] = xc @ XP2^T  (A = xc_t, at=1)
        gemm_mfma<<<dim3(1,64), 256, 0, stream>>>(
            xc, wbf + W_XP + (size_t)e*131072, nullptr, proj, projrm,
            ROWS, 128, 1024, nullptr, 0, 0, 0, 1, 1, flag);
        // dtg_t = softplus(proj_rm @ DT2^T + dt_b)^T : [1024][8192]  (at=0)
        gemm_mfma<<<dim3(8,64), 256, 0, stream>>>(
            projrm, wbf + W_DT + (size_t)e*131072, nullptr, dtg, nullptr,
            ROWS, 1024, 128, dt_b, (size_t)e*1024, 1, 0, 0, 1, flag);
        ssm_scan<<<1024, 256, 0, stream>>>(dtg, xc, proj, xz, A_log, D_skip, e, flag);
        // acc += g @ OUT2^T : [8192,512]  (A = g_t, at=1)
        gemm_mfma<<<dim3(4,64), 256, 0, stream>>>(
            dtg, wbf + W_OUT + (size_t)e*524288, acc, nullptr, nullptr,
            ROWS, 512, 1024, nullptr, 0, 0, 1, 1, 0, flag);
        size_t eo = (size_t)e * 512;
        lnorm<<<2048, 256, 0, stream>>>(nullptr, acc, n1_w, eo, n1_b, eo, x1, 0, flag);
        gemm_mfma<<<dim3(16,64), 256, 0, stream>>>(
            x1, wbf + W_FF1 + (size_t)e*1048576, nullptr, ffh, nullptr,
            ROWS, 2048, 512, ffn1_b, (size_t)e*2048, 2, 0, 0, 0, flag);
        gemm_mfma<<<dim3(4,64), 256, 0, stream>>>(
            ffh, wbf + W_FF2 + (size_t)e*1048576, y2, nullptr, nullptr,
            ROWS, 512, 2048, ffn2_b, eo, 0, 0, 0, 0, flag);
        lnorm<<<2048, 256, 0, stream>>>(x1, y2, n2_w, eo, n2_b, eo, cur, 0, flag);
    }
    lnorm<<<2048, 256, 0, stream>>>(cur, nullptr, fn_w, 0, fn_b, 0, d_out, 1, flag);
}